// Round 1
// baseline (906.025 us; speedup 1.0000x reference)
//
#include <hip/hip_runtime.h>
#include <stdint.h>

#define LOGZERO (-1e10f)

static constexpr int BS    = 32;
static constexpr int XMAX  = 1024;
static constexpr int VOCAB = 1000;
static constexpr int YMAX  = 128;
static constexpr int LSTATES = 2 * YMAX + 1;   // 257
static constexpr int LPAD  = 264;              // padded row length for lp_path
static constexpr int NROWS = YMAX + 1;         // 129 trigger-mask rows

// ---------------- Kernel A: gather lp_path[b][t][l] = ctc[b][t][path[l]] ----
__global__ __launch_bounds__(64) void k_gather(
    const float* __restrict__ ctc, const int* __restrict__ src_size,
    const int* __restrict__ ys, const int* __restrict__ blankp,
    float* __restrict__ lp_path)
{
    int bt = blockIdx.x;               // b*1024 + t
    int b = bt >> 10, t = bt & (XMAX - 1);
    int lane = threadIdx.x;
    int ss = src_size[b];
    if (t >= ss) return;               // rows t>=ss are never read
    int bv = blankp[0];
    const float* row  = ctc + ((size_t)b * XMAX + t) * VOCAB;
    float* orow       = lp_path + ((size_t)b * XMAX + t) * LPAD;
    #pragma unroll
    for (int l0 = 0; l0 < 320; l0 += 64) {
        int l = l0 + lane;
        if (l < LSTATES) {
            int tok = (l & 1) ? ys[b * YMAX + (l >> 1)] : bv;
            orow[l] = row[tok];
        }
    }
}

// ---------------- Kernel B: per-batch Viterbi + backtrace + csum ------------
__global__ __launch_bounds__(64) void k_viterbi(
    const float* __restrict__ ctc, const float* __restrict__ lp_path,
    const int* __restrict__ src_size, const int* __restrict__ ys,
    const int* __restrict__ ylens, const int* __restrict__ blankp,
    int staged, int* __restrict__ csum_ws, float* __restrict__ out)
{
    // 2-bit back-pointers, ballot-packed: per t, 5 chunks x (bit0,bit1) u64
    __shared__ ulonglong2 bpb[XMAX][5];            // 80 KB
    __shared__ float afin[LSTATES];                // final alpha
    __shared__ unsigned short st_lds[XMAX];        // backtraced states
    __shared__ int ysl[YMAX];

    const int b    = blockIdx.x;
    const int lane = threadIdx.x;
    const int ss   = src_size[b];
    const int yl   = ylens[b];
    const int bv   = blankp[0];
    const int plen = 2 * yl + 1;
    const float LZ = LOGZERO;

    for (int j = lane; j < YMAX; j += 64) ysl[j] = ys[b * YMAX + j];
    for (int t = lane; t < XMAX; t += 64) st_lds[t] = 0;
    __syncthreads();

    // per-lane path tokens & allow-skip flags for each chunk (l = k*64+lane)
    auto tok_of = [&](int l) -> int {
        return (l & 1) ? ys[b * YMAX + (l >> 1)] : bv;
    };
    auto allow2_of = [&](int l, int tok) -> bool {
        if (!(l & 1) || l < 3) return false;       // even l: blank==blank; l<2: none
        return tok != ys[b * YMAX + (l >> 1) - 1];
    };
    const int tok0 = tok_of(lane),       tok1 = tok_of(64 + lane);
    const int tok2 = tok_of(128 + lane), tok3 = tok_of(192 + lane);
    const bool al0 = allow2_of(lane, tok0),       al1 = allow2_of(64 + lane, tok1);
    const bool al2 = allow2_of(128 + lane, tok2), al3 = allow2_of(192 + lane, tok3);
    const bool o0 = (lane >= plen),       o1 = (64 + lane >= plen);
    const bool o2 = (128 + lane >= plen), o3 = (192 + lane >= plen);
    const bool o4 = (256 >= plen);

    float a0 = (lane == 0) ? 0.0f : LZ;
    float a1 = LZ, a2 = LZ, a3 = LZ, a4 = LZ;

    const float* ctcb = ctc + (size_t)b * XMAX * VOCAB;
    const float* lpb  = lp_path + (size_t)b * XMAX * LPAD;
    auto loadlp = [&](int t, float& c0, float& c1, float& c2, float& c3, float& c4) {
        if (staged) {
            const float* r = lpb + (size_t)t * LPAD;
            c0 = r[lane]; c1 = r[64 + lane]; c2 = r[128 + lane]; c3 = r[192 + lane];
            c4 = (lane == 0) ? r[256] : LZ;
        } else {
            const float* r = ctcb + (size_t)t * VOCAB;
            c0 = r[tok0]; c1 = r[tok1]; c2 = r[tok2]; c3 = r[tok3];
            c4 = (lane == 0) ? r[bv] : LZ;
        }
    };

    // one chunk step: reads OLD alphas (ak = this chunk, akm1 = previous chunk)
    auto chunk = [&](float ak, float akm1, bool allow2, bool outside, float lp,
                     int& argo) -> float {
        float p1 = __shfl_up(ak, 1);
        float f1 = __shfl(akm1, 63);
        p1 = (lane == 0) ? f1 : p1;
        float p2 = __shfl_up(ak, 2);
        float f2 = __shfl(akm1, 62 + lane);   // lanes 0,1 take chunk k-1 lanes 62,63
        p2 = (lane < 2) ? f2 : p2;
        p2 = allow2 ? p2 : LZ;
        float m = ak; int arg = 0;            // strict '>' = first-max tie-break
        if (p1 > m) { m = p1; arg = 1; }
        if (p2 > m) { m = p2; arg = 2; }
        argo = arg;
        m = outside ? LZ : m;
        return m + lp;
    };

    float c0, c1, c2, c3, c4;
    loadlp(0, c0, c1, c2, c3, c4);
    for (int t = 0; t < ss; ++t) {
        float d0, d1, d2, d3, d4;
        int tn = (t + 1 < ss) ? (t + 1) : t;   // depth-1 prefetch
        loadlp(tn, d0, d1, d2, d3, d4);

        int g0, g1, g2, g3;
        float n0 = chunk(a0, LZ, al0, o0, c0, g0);
        float n1 = chunk(a1, a0, al1, o1, c1, g1);
        float n2 = chunk(a2, a1, al2, o2, c2, g2);
        float n3 = chunk(a3, a2, al3, o3, c3, g3);
        // chunk 4: only state 256 (even -> no skip transition)
        float p41 = __shfl(a3, 63);
        float m4 = a4; int g4 = 0;
        if (p41 > m4) { m4 = p41; g4 = 1; }
        m4 = o4 ? LZ : m4;
        float n4 = (lane == 0) ? (m4 + c4) : LZ;

        unsigned long long q00 = __ballot(g0 & 1), q01 = __ballot(g0 & 2);
        unsigned long long q10 = __ballot(g1 & 1), q11 = __ballot(g1 & 2);
        unsigned long long q20 = __ballot(g2 & 1), q21 = __ballot(g2 & 2);
        unsigned long long q30 = __ballot(g3 & 1), q31 = __ballot(g3 & 2);
        unsigned long long q40 = __ballot(g4 & 1);
        if (lane == 0) {
            bpb[t][0] = make_ulonglong2(q00, q01);
            bpb[t][1] = make_ulonglong2(q10, q11);
            bpb[t][2] = make_ulonglong2(q20, q21);
            bpb[t][3] = make_ulonglong2(q30, q31);
            bpb[t][4] = make_ulonglong2(q40, 0ULL);
        }
        a0 = n0; a1 = n1; a2 = n2; a3 = n3; a4 = n4;
        c0 = d0; c1 = d1; c2 = d2; c3 = d3; c4 = d4;
    }

    // final alpha -> LDS, pick score & start state
    afin[lane] = a0; afin[64 + lane] = a1; afin[128 + lane] = a2; afin[192 + lane] = a3;
    if (lane == 0) afin[256] = a4;
    __syncthreads();
    const float s1 = afin[plen - 1], s2 = afin[plen - 2];
    const float score = (s1 > s2) ? s1 : s2;
    const int start = (s1 > s2) ? (plen - 1) : (plen - 2);
    if (lane == 0) {
        out[b] = score;                                        // output 0
        out[32 + (size_t)BS * NROWS * XMAX + b] = (float)(yl + 1);  // output 2
    }

    // sequential backtrace (lane 0), dependent LDS chain
    if (lane == 0) {
        int s = start;
        st_lds[ss - 1] = (unsigned short)s;
        for (int t = ss - 2; t >= 0; --t) {
            ulonglong2 w = bpb[t + 1][s >> 6];
            int bit = s & 63;
            int arg = (int)((w.x >> bit) & 1ULL) | ((int)((w.y >> bit) & 1ULL) << 1);
            s -= arg;
            st_lds[t] = (unsigned short)s;
        }
    }
    __syncthreads();

    // aligned tokens -> collapse repeats -> csum (count of non-blank before t)
    auto tok_lds = [&](int stv) -> int { return (stv & 1) ? ysl[stv >> 1] : bv; };
    const int t0 = lane * 16;
    int prev_raw = (t0 == 0) ? 0 : tok_lds(st_lds[t0 - 1]);
    int cnt = 0;
    int csl[16];
    #pragma unroll
    for (int i = 0; i < 16; ++i) {
        int raw = tok_lds(st_lds[t0 + i]);
        int ac = (raw == prev_raw) ? 0 : raw;   // collapsed token
        prev_raw = raw;
        csl[i] = cnt;                            // in-window count before t
        cnt += (ac != bv) ? 1 : 0;
    }
    int v = cnt;                                 // wave exclusive scan of totals
    #pragma unroll
    for (int off = 1; off < 64; off <<= 1) {
        int u = __shfl_up(v, off);
        if (lane >= off) v += u;
    }
    const int base = v - cnt;
    int* co = csum_ws + b * XMAX + t0;
    #pragma unroll
    for (int i = 0; i < 16; ++i) co[i] = base + csl[i];
}

// ---------------- Kernel C: trigger mask as 0/1 floats ----------------------
__global__ __launch_bounds__(256) void k_mask(
    const int* __restrict__ csum_ws, const int* __restrict__ src_size,
    float* __restrict__ out)
{
    int bj = blockIdx.x;
    int b = bj / NROWS, j = bj - b * NROWS;
    int ss = src_size[b];
    const int* cs = csum_ws + b * XMAX;
    float* orow = out + 32 + (size_t)bj * XMAX;
    int t = threadIdx.x * 4;
    float4 v;
    float* vp = &v.x;
    #pragma unroll
    for (int i = 0; i < 4; ++i) {
        int tt = t + i;
        int c = cs[tt];
        bool in = tt < ss;
        bool val;
        if (j < YMAX) val = (c == j) && in;
        else          val = ((c == YMAX) || (tt == ss - 1)) && in;
        vp[i] = val ? 1.0f : 0.0f;
    }
    *(float4*)(orow + t) = v;
}

extern "C" void kernel_launch(void* const* d_in, const int* in_sizes, int n_in,
                              void* d_out, int out_size, void* d_ws, size_t ws_size,
                              hipStream_t stream) {
    const float* ctc      = (const float*)d_in[0];
    // d_in[1] = src_mask (derived from src_size; unused)
    const int*   src_size = (const int*)d_in[2];
    const int*   ys       = (const int*)d_in[3];
    const int*   ylens    = (const int*)d_in[4];
    const int*   blankp   = (const int*)d_in[5];
    float* out = (float*)d_out;

    size_t lp_bytes = (size_t)BS * XMAX * LPAD * sizeof(float);
    size_t cs_bytes = (size_t)BS * XMAX * sizeof(int);
    int staged = (ws_size >= lp_bytes + cs_bytes) ? 1 : 0;
    float* lp_path = (float*)d_ws;
    int*   csum_ws = staged ? (int*)((char*)d_ws + lp_bytes) : (int*)d_ws;

    if (staged)
        k_gather<<<BS * XMAX, 64, 0, stream>>>(ctc, src_size, ys, blankp, lp_path);
    k_viterbi<<<BS, 64, 0, stream>>>(ctc, lp_path, src_size, ys, ylens, blankp,
                                     staged, csum_ws, out);
    k_mask<<<BS * NROWS, 256, 0, stream>>>(csum_ws, src_size, out);
}

// Round 2
// 607.496 us; speedup vs baseline: 1.4914x; 1.4914x over previous
//
#include <hip/hip_runtime.h>
#include <stdint.h>

#define LOGZERO (-1e10f)

static constexpr int BS    = 32;
static constexpr int XMAX  = 1024;
static constexpr int VOCAB = 1000;
static constexpr int YMAX  = 128;
static constexpr int NROWS = YMAX + 1;         // 129 trigger-mask rows
static constexpr int D     = 16;               // prefetch ring depth

// ---------------- Kernel B: per-batch fused Viterbi + backtrace + csum ------
// Layout: lane i holds states 4i..4i+3 (a0..a3); state 256 wave-uniform (a4).
// Even states are blank; skip transition never enters an even state.
__global__ __launch_bounds__(64) void k_viterbi(
    const float* __restrict__ ctc, const int* __restrict__ src_size,
    const int* __restrict__ ys, const int* __restrict__ ylens,
    const int* __restrict__ blankp, int* __restrict__ csum_ws,
    float* __restrict__ out)
{
    __shared__ unsigned char bpb[XMAX * 64];   // 64 KB: 2-bit args x4, byte/lane
    __shared__ unsigned char bp256[XMAX];      // 1 KB: state-256 arg
    __shared__ float afin[260];                // final alpha
    __shared__ unsigned short st_lds[XMAX];    // backtraced states
    __shared__ int ysl[YMAX];

    const int b    = blockIdx.x;
    const int lane = threadIdx.x;
    const int ss   = src_size[b];
    const int yl   = ylens[b];
    const int bv   = blankp[0];
    const int plen = 2 * yl + 1;
    const float LZ = LOGZERO;

    for (int j = lane; j < YMAX; j += 64) ysl[j] = ys[b * YMAX + j];
    for (int t = lane; t < XMAX; t += 64) st_lds[t] = 0;
    __syncthreads();

    const int tokA = ysl[2 * lane];            // state 4i+1
    const int tokB = ysl[2 * lane + 1];        // state 4i+3
    // skip legality (same_tr): odd state s, allowed iff s>=3 && ys[s>>1]!=ys[(s>>1)-1]
    const bool al1 = (lane > 0) && (tokA != ysl[2 * lane - 1]);
    const bool al3 = (tokB != tokA);
    const bool o0 = (4 * lane     >= plen);
    const bool o1 = (4 * lane + 1 >= plen);
    const bool o2 = (4 * lane + 2 >= plen);
    const bool o3 = (4 * lane + 3 >= plen);
    const bool o4 = (256 >= plen);

    float a0 = (lane == 0) ? 0.0f : LZ;
    float a1 = LZ, a2 = LZ, a3 = LZ, a4 = LZ;

    const float* base = ctc + (size_t)b * XMAX * VOCAB;

    // depth-D register ring: blank (broadcast), tokA, tokB per future row
    float rB[D], r1[D], r3[D];
    #pragma unroll
    for (int d = 0; d < D; ++d) {
        int t = (d < ss) ? d : (ss - 1);
        const float* r = base + (size_t)t * VOCAB;
        rB[d] = r[bv]; r1[d] = r[tokA]; r3[d] = r[tokB];
    }

    const int ntile = (ss + D - 1) / D;
    for (int tile = 0; tile < ntile; ++tile) {
        #pragma unroll
        for (int d = 0; d < D; ++d) {
            const int t = tile * D + d;
            const float cb = rB[d], c1v = r1[d], c3v = r3[d];
            {   // issue refill for row t+D (clamped; values unused past ss)
                int tn = t + D; if (tn >= ss) tn = ss - 1;
                const float* r = base + (size_t)tn * VOCAB;
                rB[d] = r[bv]; r1[d] = r[tokA]; r3[d] = r[tokB];
            }
            if (t < ss) {
                float p3 = __shfl_up(a3, 1);           // state 4i-1 (prev lane e3)
                p3 = (lane == 0) ? LZ : p3;
                float a3_63 = __shfl(a3, 63);          // state 255 for s=256

                // strict '>' replicates jnp.argmax first-max tie-break
                float m0 = a0; int g0 = 0; if (p3 > m0) { m0 = p3; g0 = 1; }
                float m1 = a1; int g1 = 0; if (a0 > m1) { m1 = a0; g1 = 1; }
                float sk1 = al1 ? p3 : LZ;  if (sk1 > m1) { m1 = sk1; g1 = 2; }
                float m2 = a2; int g2 = 0; if (a1 > m2) { m2 = a1; g2 = 1; }
                float m3 = a3; int g3 = 0; if (a2 > m3) { m3 = a2; g3 = 1; }
                float sk3 = al3 ? a1 : LZ;  if (sk3 > m3) { m3 = sk3; g3 = 2; }
                float m4 = a4; int g4 = 0; if (a3_63 > m4) { m4 = a3_63; g4 = 1; }

                a0 = (o0 ? LZ : m0) + cb;
                a1 = (o1 ? LZ : m1) + c1v;
                a2 = (o2 ? LZ : m2) + cb;
                a3 = (o3 ? LZ : m3) + c3v;
                a4 = (o4 ? LZ : m4) + cb;

                bpb[t * 64 + lane] =
                    (unsigned char)(g0 | (g1 << 2) | (g2 << 4) | (g3 << 6));
                if (lane == 0) bp256[t] = (unsigned char)g4;
            }
        }
    }

    // final alpha -> LDS, pick score & start state
    afin[4 * lane]     = a0;
    afin[4 * lane + 1] = a1;
    afin[4 * lane + 2] = a2;
    afin[4 * lane + 3] = a3;
    if (lane == 0) afin[256] = a4;
    __syncthreads();
    const float s1 = afin[plen - 1], s2 = afin[plen - 2];
    const float score = (s1 > s2) ? s1 : s2;
    const int start = (s1 > s2) ? (plen - 1) : (plen - 2);
    if (lane == 0) {
        out[b] = score;                                         // output 0
        out[32 + (size_t)BS * NROWS * XMAX + b] = (float)(yl + 1);  // output 2
    }

    // sequential backtrace (lane 0), dependent LDS byte chain
    if (lane == 0) {
        int s = start;
        st_lds[ss - 1] = (unsigned short)s;
        for (int t = ss - 2; t >= 0; --t) {
            int arg;
            if (s == 256) {
                arg = bp256[t + 1];
            } else {
                int byv = bpb[(t + 1) * 64 + (s >> 2)];
                arg = (byv >> ((s & 3) * 2)) & 3;
            }
            s -= arg;
            st_lds[t] = (unsigned short)s;
        }
    }
    __syncthreads();

    // aligned tokens -> collapse repeats -> csum (count of non-blank before t)
    auto tok_lds = [&](int stv) -> int { return (stv & 1) ? ysl[stv >> 1] : bv; };
    const int t0 = lane * 16;
    int prev_raw = (t0 == 0) ? 0 : tok_lds(st_lds[t0 - 1]);
    int cnt = 0;
    int csl[16];
    #pragma unroll
    for (int i = 0; i < 16; ++i) {
        int raw = tok_lds(st_lds[t0 + i]);
        int ac = (raw == prev_raw) ? 0 : raw;   // collapsed token
        prev_raw = raw;
        csl[i] = cnt;                            // in-window count before t
        cnt += (ac != bv) ? 1 : 0;
    }
    int v = cnt;                                 // wave exclusive scan of totals
    #pragma unroll
    for (int off = 1; off < 64; off <<= 1) {
        int u = __shfl_up(v, off);
        if (lane >= off) v += u;
    }
    const int base_c = v - cnt;
    int* co = csum_ws + b * XMAX + t0;
    #pragma unroll
    for (int i = 0; i < 16; ++i) co[i] = base_c + csl[i];
}

// ---------------- Kernel C: trigger mask as 0/1 floats ----------------------
__global__ __launch_bounds__(256) void k_mask(
    const int* __restrict__ csum_ws, const int* __restrict__ src_size,
    float* __restrict__ out)
{
    int bj = blockIdx.x;
    int b = bj / NROWS, j = bj - b * NROWS;
    int ss = src_size[b];
    const int* cs = csum_ws + b * XMAX;
    float* orow = out + 32 + (size_t)bj * XMAX;
    int t = threadIdx.x * 4;
    float4 v;
    float* vp = &v.x;
    #pragma unroll
    for (int i = 0; i < 4; ++i) {
        int tt = t + i;
        int c = cs[tt];
        bool in = tt < ss;
        bool val;
        if (j < YMAX) val = (c == j) && in;
        else          val = ((c == YMAX) || (tt == ss - 1)) && in;
        vp[i] = val ? 1.0f : 0.0f;
    }
    *(float4*)(orow + t) = v;
}

extern "C" void kernel_launch(void* const* d_in, const int* in_sizes, int n_in,
                              void* d_out, int out_size, void* d_ws, size_t ws_size,
                              hipStream_t stream) {
    const float* ctc      = (const float*)d_in[0];
    // d_in[1] = src_mask (derived from src_size; unused)
    const int*   src_size = (const int*)d_in[2];
    const int*   ys       = (const int*)d_in[3];
    const int*   ylens    = (const int*)d_in[4];
    const int*   blankp   = (const int*)d_in[5];
    float* out = (float*)d_out;
    int*   csum_ws = (int*)d_ws;   // 32*1024*4 = 128 KB

    k_viterbi<<<BS, 64, 0, stream>>>(ctc, src_size, ys, ylens, blankp,
                                     csum_ws, out);
    k_mask<<<BS * NROWS, 256, 0, stream>>>(csum_ws, src_size, out);
}